// Round 1
// baseline (4528.822 us; speedup 1.0000x reference)
//
#include <hip/hip_runtime.h>
#include <hip/hip_bf16.h>

#define B_ 512
#define T_ 128
#define DIN_ 256
#define H_ 512

typedef __attribute__((ext_vector_type(8))) short short8;
typedef __attribute__((ext_vector_type(4))) float f32x4;

__device__ __forceinline__ float sigm(float x) { return 1.0f / (1.0f + __expf(-x)); }

// Convert weights f32->bf16 and initialize h state (f32 master + bf16 parity-1 buffer).
__global__ void prep_kernel(const float* __restrict__ wih0, const float* __restrict__ whh0,
                            const float* __restrict__ wih1, const float* __restrict__ whh1,
                            const float* __restrict__ h_in,
                            __hip_bfloat16* __restrict__ bwih0, __hip_bfloat16* __restrict__ bwhh0,
                            __hip_bfloat16* __restrict__ bwih1, __hip_bfloat16* __restrict__ bwhh1,
                            float* __restrict__ h0f, float* __restrict__ h1f,
                            __hip_bfloat16* __restrict__ h0b1, __hip_bfloat16* __restrict__ h1b1)
{
    int tid = blockIdx.x * blockDim.x + threadIdx.x;
    int stride = gridDim.x * blockDim.x;
    for (int i = tid; i < 1536 * DIN_; i += stride) bwih0[i] = __float2bfloat16(wih0[i]);
    for (int i = tid; i < 1536 * H_;   i += stride) bwhh0[i] = __float2bfloat16(whh0[i]);
    for (int i = tid; i < 1536 * H_;   i += stride) bwih1[i] = __float2bfloat16(wih1[i]);
    for (int i = tid; i < 1536 * H_;   i += stride) bwhh1[i] = __float2bfloat16(whh1[i]);
    for (int i = tid; i < B_ * H_; i += stride) {
        int b = i >> 9, j = i & (H_ - 1);
        float v0 = h_in[((size_t)b * 2 + 0) * H_ + j];
        float v1 = h_in[((size_t)b * 2 + 1) * H_ + j];
        h0f[i] = v0; h1f[i] = v1;
        h0b1[i] = __float2bfloat16(v0);
        h1b1[i] = __float2bfloat16(v1);
    }
}

// One pipeline slot t: blocks 0..127 -> layer0 step t (if t<T_),
//                      blocks 128..255 -> layer1 step t-1 (if t>=1).
// Block tile: 64 batch rows x 32 hidden j, all 3 gates (N=96 of the 1536 gate matrix).
__global__ __launch_bounds__(256) void gru_step(
    int t,
    const float* __restrict__ x,
    const int* __restrict__ is_init,
    const float* __restrict__ b_ih0, const float* __restrict__ b_hh0,
    const float* __restrict__ b_ih1, const float* __restrict__ b_hh1,
    const __hip_bfloat16* __restrict__ wih0, const __hip_bfloat16* __restrict__ whh0,
    const __hip_bfloat16* __restrict__ wih1, const __hip_bfloat16* __restrict__ whh1,
    float* __restrict__ h0f, float* __restrict__ h1f,
    __hip_bfloat16* __restrict__ h0b,   // 2 x [512*512] ping-pong
    __hip_bfloat16* __restrict__ h1b,   // 2 x [512*512] ping-pong
    float* __restrict__ out)            // [B,T,H]
{
    const int role = blockIdx.x >> 7;
    int s;
    if (role == 0) { if (t >= T_) return; s = t; }
    else           { if (t == 0)  return; s = t - 1; }

    const int rel = blockIdx.x & 127;
    const int bt = rel >> 4;   // 8 batch tiles of 64
    const int jt = rel & 15;   // 16 hidden tiles of 32
    const int b0 = bt * 64;

    const __hip_bfloat16 *Wi, *Wh;
    const float *bi, *bh;
    const __hip_bfloat16* Xb = nullptr;   // bf16 input rows (layer1 only)
    int KI;
    const __hip_bfloat16* Hprev;
    float* Hf;
    __hip_bfloat16* Hout;
    const size_t HS = (size_t)B_ * H_;

    if (role == 0) {
        Wi = wih0; Wh = whh0; bi = b_ih0; bh = b_hh0; KI = DIN_;
        Hprev = h0b + ((size_t)((s + 1) & 1)) * HS;   // state after s-1
        Hout  = h0b + ((size_t)(s & 1)) * HS;
        Hf = h0f;
    } else {
        Wi = wih1; Wh = whh1; bi = b_ih1; bh = b_hh1; KI = H_;
        Xb    = h0b + ((size_t)(s & 1)) * HS;          // h0 state after step s
        Hprev = h1b + ((size_t)((s + 1) & 1)) * HS;
        Hout  = h1b + ((size_t)(s & 1)) * HS;
        Hf = h1f;
    }

    __shared__ __align__(16) __hip_bfloat16 ldsA[64 * 40];
    __shared__ __align__(16) __hip_bfloat16 ldsB[96 * 40];

    const int tidx = threadIdx.x;
    const int lane = tidx & 63;
    const int w = tidx >> 6;
    const int l15 = lane & 15;
    const int kg = (lane >> 4) * 8;

    f32x4 acc_i[6] = {f32x4{0,0,0,0},f32x4{0,0,0,0},f32x4{0,0,0,0},f32x4{0,0,0,0},f32x4{0,0,0,0},f32x4{0,0,0,0}};
    f32x4 acc_h[6] = {f32x4{0,0,0,0},f32x4{0,0,0,0},f32x4{0,0,0,0},f32x4{0,0,0,0},f32x4{0,0,0,0},f32x4{0,0,0,0}};

    // A-staging thread coords (64 rows x 4 quarters of 8 elems)
    const int arow = tidx >> 2;
    const int aq = tidx & 3;
    const int ab = b0 + arow;
    const bool ainit = (is_init[ab * T_ + s] != 0);

    const int KTOT = KI + H_;
    for (int k0 = 0; k0 < KTOT; k0 += 32) {
        const bool ph = (k0 >= KI);
        const int kk = ph ? (k0 - KI) : k0;

        // ---- stage A tile [64][32] ----
        if (role == 0 && !ph) {
            const float* src = x + ((size_t)ab * T_ + s) * DIN_ + kk + aq * 8;
            float4 u = *(const float4*)src;
            float4 v = *(const float4*)(src + 4);
            __hip_bfloat16 tmp[8];
            tmp[0] = __float2bfloat16(u.x); tmp[1] = __float2bfloat16(u.y);
            tmp[2] = __float2bfloat16(u.z); tmp[3] = __float2bfloat16(u.w);
            tmp[4] = __float2bfloat16(v.x); tmp[5] = __float2bfloat16(v.y);
            tmp[6] = __float2bfloat16(v.z); tmp[7] = __float2bfloat16(v.w);
            *(uint4*)&ldsA[arow * 40 + aq * 8] = *(const uint4*)tmp;
        } else {
            const __hip_bfloat16* base = ph ? Hprev : Xb;
            uint4 v = *(const uint4*)(base + (size_t)ab * H_ + kk + aq * 8);
            if (ph && ainit) v = make_uint4(0, 0, 0, 0);
            *(uint4*)&ldsA[arow * 40 + aq * 8] = v;
        }

        // ---- stage B tile [96][32] (3 gates x 32 n-rows) ----
        if (tidx < 192) {
            const int rowb = tidx >> 1;
            const int half = tidx & 1;
            const int g = rowb >> 5;
            const int n = rowb & 31;
            const int wrow = g * H_ + jt * 32 + n;
            const __hip_bfloat16* Wsrc = ph ? Wh : Wi;
            const int wK = ph ? H_ : KI;
            const __hip_bfloat16* src = Wsrc + (size_t)wrow * wK + kk + half * 16;
            uint4 v0 = *(const uint4*)src;
            uint4 v1 = *(const uint4*)(src + 8);
            *(uint4*)&ldsB[rowb * 40 + half * 16]     = v0;
            *(uint4*)&ldsB[rowb * 40 + half * 16 + 8] = v1;
        }
        __syncthreads();

        short8 a = *(const short8*)&ldsA[(w * 16 + l15) * 40 + kg];
        if (!ph) {
#pragma unroll
            for (int f = 0; f < 6; ++f) {
                short8 bfr = *(const short8*)&ldsB[((f >> 1) * 32 + (f & 1) * 16 + l15) * 40 + kg];
                acc_i[f] = __builtin_amdgcn_mfma_f32_16x16x32_bf16(a, bfr, acc_i[f], 0, 0, 0);
            }
        } else {
#pragma unroll
            for (int f = 0; f < 6; ++f) {
                short8 bfr = *(const short8*)&ldsB[((f >> 1) * 32 + (f & 1) * 16 + l15) * 40 + kg];
                acc_h[f] = __builtin_amdgcn_mfma_f32_16x16x32_bf16(a, bfr, acc_h[f], 0, 0, 0);
            }
        }
        __syncthreads();
    }

    // ---- fused gate epilogue ----
#pragma unroll
    for (int c = 0; c < 2; ++c) {
        const int j = jt * 32 + c * 16 + l15;
        const float bir  = bi[j],          bhr = bh[j];
        const float biz  = bi[H_ + j],     bhz = bh[H_ + j];
        const float bin_ = bi[2 * H_ + j], bhn = bh[2 * H_ + j];
#pragma unroll
        for (int r = 0; r < 4; ++r) {
            const int m = w * 16 + (lane >> 4) * 4 + r;
            const int b = b0 + m;
            const float vir = acc_i[c][r] + bir;
            const float vhr = acc_h[c][r] + bhr;
            const float viz = acc_i[2 + c][r] + biz;
            const float vhz = acc_h[2 + c][r] + bhz;
            const float vin = acc_i[4 + c][r] + bin_;
            const float vhn = acc_h[4 + c][r] + bhn;
            const float rr = sigm(vir + vhr);
            const float zz = sigm(viz + vhz);
            const float nn = tanhf(vin + rr * vhn);
            const bool ini = (is_init[b * T_ + s] != 0);
            const float hp = ini ? 0.0f : Hf[(size_t)b * H_ + j];
            const float hnew = (1.0f - zz) * nn + zz * hp;
            Hf[(size_t)b * H_ + j] = hnew;
            Hout[(size_t)b * H_ + j] = __float2bfloat16(hnew);
            if (role == 1) out[((size_t)b * T_ + s) * H_ + j] = hnew;
        }
    }
}

__global__ void finalize_kernel(const float* __restrict__ h0f, const float* __restrict__ h1f,
                                float* __restrict__ out_hn)
{
    int i = blockIdx.x * blockDim.x + threadIdx.x;
    if (i < B_ * H_) {
        int b = i >> 9, j = i & (H_ - 1);
        out_hn[((size_t)b * 2 + 0) * H_ + j] = h0f[i];
        out_hn[((size_t)b * 2 + 1) * H_ + j] = h1f[i];
    }
}

extern "C" void kernel_launch(void* const* d_in, const int* in_sizes, int n_in,
                              void* d_out, int out_size, void* d_ws, size_t ws_size,
                              hipStream_t stream) {
    (void)in_sizes; (void)n_in; (void)out_size; (void)ws_size;
    const float* x     = (const float*)d_in[0];
    const int*   isin  = (const int*)d_in[1];
    const float* h_in  = (const float*)d_in[2];
    const float* wih0  = (const float*)d_in[3];
    const float* whh0  = (const float*)d_in[4];
    const float* bih0  = (const float*)d_in[5];
    const float* bhh0  = (const float*)d_in[6];
    const float* wih1  = (const float*)d_in[7];
    const float* whh1  = (const float*)d_in[8];
    const float* bih1  = (const float*)d_in[9];
    const float* bhh1  = (const float*)d_in[10];
    float* out = (float*)d_out;

    char* wsb = (char*)d_ws;
    __hip_bfloat16* bwih0 = (__hip_bfloat16*)wsb;                 // 1536*256
    __hip_bfloat16* bwhh0 = bwih0 + 1536 * DIN_;                  // 1536*512
    __hip_bfloat16* bwih1 = bwhh0 + 1536 * H_;
    __hip_bfloat16* bwhh1 = bwih1 + 1536 * H_;
    float* h0f = (float*)(wsb + 5505024);
    float* h1f = h0f + B_ * H_;
    __hip_bfloat16* h0b = (__hip_bfloat16*)(wsb + 7602176);       // 2 buffers
    __hip_bfloat16* h1b = h0b + 2 * (size_t)B_ * H_ / 2 * 2;      // == h0b + 524288

    prep_kernel<<<dim3(512), dim3(256), 0, stream>>>(
        wih0, whh0, wih1, whh1, h_in,
        bwih0, bwhh0, bwih1, bwhh1,
        h0f, h1f,
        h0b + (size_t)B_ * H_,   // parity-1 buffer (state after step -1)
        h1b + (size_t)B_ * H_);

    for (int t = 0; t <= T_; ++t) {
        gru_step<<<dim3(256), dim3(256), 0, stream>>>(
            t, x, isin, bih0, bhh0, bih1, bhh1,
            bwih0, bwhh0, bwih1, bwhh1,
            h0f, h1f, h0b, h1b, out);
    }

    finalize_kernel<<<dim3((B_ * H_ + 255) / 256), dim3(256), 0, stream>>>(
        h0f, h1f, out + (size_t)B_ * T_ * H_);
}

// Round 2
// 3042.916 us; speedup vs baseline: 1.4883x; 1.4883x over previous
//
#include <hip/hip_runtime.h>
#include <hip/hip_bf16.h>

#define B_ 512
#define T_ 128
#define DIN_ 256
#define H_ 512
#define KPAD 1048          // LDS weight row stride (bf16 elems): 524 words -> 2-way max conflict
#define WROWS 48           // 3 gates x 16 j
#define CPAD 52            // combine buffer col stride (f32)
#define HS ((size_t)B_ * H_)
#define OUT_MAIN ((size_t)B_ * T_ * H_)

typedef __attribute__((ext_vector_type(8))) short short8;
typedef __attribute__((ext_vector_type(4))) float f32x4;

__device__ __forceinline__ float sigm(float v) { return 1.0f / (1.0f + __expf(-v)); }

__device__ __forceinline__ unsigned short f2bf(float f) {
    union { __hip_bfloat16 b; unsigned short u; } c;
    c.b = __float2bfloat16(f);
    return c.u;
}

__device__ __forceinline__ short8 cvt8(const float* p) {
    float4 u = *(const float4*)p;
    float4 v = *(const float4*)(p + 4);
    short8 o;
    o[0] = (short)f2bf(u.x); o[1] = (short)f2bf(u.y);
    o[2] = (short)f2bf(u.z); o[3] = (short)f2bf(u.w);
    o[4] = (short)f2bf(v.x); o[5] = (short)f2bf(v.y);
    o[6] = (short)f2bf(v.z); o[7] = (short)f2bf(v.w);
    return o;
}

// group barrier: 64 blocks of one batch-tile group. Fresh counter per phase.
__device__ __forceinline__ void group_barrier(int* c, int n) {
    __syncthreads();   // drains vmcnt of all waves -> stores are in this XCD's L2
    if (threadIdx.x == 0) {
        __builtin_amdgcn_fence(__ATOMIC_RELEASE, "agent");   // wb L2 -> coherent point
        __hip_atomic_fetch_add(c, 1, __ATOMIC_RELAXED, __HIP_MEMORY_SCOPE_AGENT);
        while (__hip_atomic_load(c, __ATOMIC_RELAXED, __HIP_MEMORY_SCOPE_AGENT) < n)
            __builtin_amdgcn_s_sleep(2);
        __builtin_amdgcn_fence(__ATOMIC_ACQUIRE, "agent");   // inv L1+L2
    }
    __syncthreads();
}

__global__ void init_kernel(const float* __restrict__ h_in,
                            __hip_bfloat16* __restrict__ h0b,
                            __hip_bfloat16* __restrict__ h1b,
                            int* __restrict__ ctrs)
{
    int i = blockIdx.x * blockDim.x + threadIdx.x;
    if (i < 512) ctrs[i] = 0;
    if (i < (int)(B_ * H_)) {
        int b = i >> 9, j = i & (H_ - 1);
        // parity-1 buffers hold state "after step -1"
        h0b[HS + i] = __float2bfloat16(h_in[((size_t)b * 2 + 0) * H_ + j]);
        h1b[HS + i] = __float2bfloat16(h_in[((size_t)b * 2 + 1) * H_ + j]);
    }
}

// Persistent kernel. 256 blocks x 512 threads. 1 block/CU (LDS-forced).
// block -> (layer l, batch-tile bt of 128 rows, j-tile jt of 16 cols)
// waves: (mq in 0..3 -> 32 batch rows) x (part: 0=input GEMM, 1=hidden GEMM)
__global__ __launch_bounds__(512, 2) void gru_persist(
    const float* __restrict__ x, const int* __restrict__ is_init,
    const float* __restrict__ h_in,
    const float* __restrict__ wih0, const float* __restrict__ whh0,
    const float* __restrict__ bih0, const float* __restrict__ bhh0,
    const float* __restrict__ wih1, const float* __restrict__ whh1,
    const float* __restrict__ bih1, const float* __restrict__ bhh1,
    __hip_bfloat16* __restrict__ h0b, __hip_bfloat16* __restrict__ h1b,
    int* __restrict__ ctrs, float* __restrict__ out)
{
    __shared__ __hip_bfloat16 wlds[WROWS * KPAD];   // 100608 B
    __shared__ float cmb[4 * 32 * CPAD];            //  26624 B

    const int bid = blockIdx.x;
    const int l   = bid >> 7;
    const int bt  = (bid >> 5) & 3;
    const int jt  = bid & 31;
    const int tid = threadIdx.x;
    const int lane = tid & 63;
    const int wid  = tid >> 6;
    const int mq   = wid >> 1;
    const int part = wid & 1;
    const int l15  = lane & 15;
    const int kg   = (lane >> 4) * 8;
    const int qr4  = (lane >> 4) * 4;
    const int rb   = bt * 128 + mq * 32;
    const int j    = jt * 16 + l15;

    const float* Wi = l ? wih1 : wih0;
    const float* Wh = l ? whh1 : whh0;
    const float* bi = l ? bih1 : bih0;
    const float* bh = l ? bhh1 : bhh0;
    const int KI = l ? H_ : DIN_;

    // ---- stage weight slice to LDS (f32 -> bf16), once ----
    {
        const int nci = KI / 8;
        for (int idx = tid; idx < WROWS * nci; idx += 512) {
            int r = idx / nci, c8 = idx - r * nci;
            int grow = (r >> 4) * H_ + jt * 16 + (r & 15);
            *(short8*)&wlds[r * KPAD + c8 * 8] = cvt8(Wi + (size_t)grow * KI + c8 * 8);
        }
        for (int idx = tid; idx < WROWS * 64; idx += 512) {
            int r = idx >> 6, c8 = idx & 63;
            int grow = (r >> 4) * H_ + jt * 16 + (r & 15);
            *(short8*)&wlds[r * KPAD + 512 + c8 * 8] = cvt8(Wh + (size_t)grow * H_ + c8 * 8);
        }
    }

    // ---- hoisted per-lane constants ----
    float hp[2][4];   // h-prev master (h-waves use; rows mm*16+qr4+r, col j)
    #pragma unroll
    for (int mm = 0; mm < 2; ++mm)
        #pragma unroll
        for (int r = 0; r < 4; ++r)
            hp[mm][r] = h_in[((size_t)(rb + mm * 16 + qr4 + r) * 2 + l) * H_ + j];
    const float b_r  = bi[j] + bh[j];
    const float b_z  = bi[H_ + j] + bh[H_ + j];
    const float b_in = bi[2 * H_ + j];
    const float b_hn = bh[2 * H_ + j];

    __syncthreads();

    const short8 zed = {0, 0, 0, 0, 0, 0, 0, 0};

    for (int t = 0; t <= T_; ++t) {
        const int s = l ? (t - 1) : t;
        const bool active = (s >= 0) && (s < T_);

        f32x4 acc[2][3];
        #pragma unroll
        for (int mm = 0; mm < 2; ++mm)
            #pragma unroll
            for (int g = 0; g < 3; ++g)
                acc[mm][g] = f32x4{0.f, 0.f, 0.f, 0.f};

        if (active) {
            if (part == 0) {
                // ---- input-side GEMM (gi) ----
                if (l == 0) {
                    const float* xr0 = x + ((size_t)(rb + l15) * T_ + s) * DIN_ + kg;
                    const float* xr1 = x + ((size_t)(rb + 16 + l15) * T_ + s) * DIN_ + kg;
                    for (int k0 = 0; k0 < DIN_; k0 += 32) {
                        short8 a0 = cvt8(xr0 + k0);
                        short8 a1 = cvt8(xr1 + k0);
                        #pragma unroll
                        for (int g = 0; g < 3; ++g) {
                            short8 bf = *(const short8*)&wlds[(g * 16 + l15) * KPAD + k0 + kg];
                            acc[0][g] = __builtin_amdgcn_mfma_f32_16x16x32_bf16(a0, bf, acc[0][g], 0, 0, 0);
                            acc[1][g] = __builtin_amdgcn_mfma_f32_16x16x32_bf16(a1, bf, acc[1][g], 0, 0, 0);
                        }
                    }
                } else {
                    const __hip_bfloat16* hs = h0b + (size_t)(s & 1) * HS;
                    const __hip_bfloat16* r0 = hs + (size_t)(rb + l15) * H_ + kg;
                    const __hip_bfloat16* r1 = hs + (size_t)(rb + 16 + l15) * H_ + kg;
                    for (int k0 = 0; k0 < H_; k0 += 32) {
                        short8 a0 = *(const short8*)(r0 + k0);
                        short8 a1 = *(const short8*)(r1 + k0);
                        #pragma unroll
                        for (int g = 0; g < 3; ++g) {
                            short8 bf = *(const short8*)&wlds[(g * 16 + l15) * KPAD + k0 + kg];
                            acc[0][g] = __builtin_amdgcn_mfma_f32_16x16x32_bf16(a0, bf, acc[0][g], 0, 0, 0);
                            acc[1][g] = __builtin_amdgcn_mfma_f32_16x16x32_bf16(a1, bf, acc[1][g], 0, 0, 0);
                        }
                    }
                }
                // dump gi to combine buffer
                #pragma unroll
                for (int mm = 0; mm < 2; ++mm)
                    #pragma unroll
                    for (int g = 0; g < 3; ++g)
                        #pragma unroll
                        for (int r = 0; r < 4; ++r)
                            cmb[(mq * 32 + mm * 16 + qr4 + r) * CPAD + g * 16 + l15] = acc[mm][g][r];
            } else {
                // ---- hidden-side GEMM (gh), with per-row is_init zeroing ----
                const __hip_bfloat16* hs = (l ? h1b : h0b) + (size_t)((s + 1) & 1) * HS;
                const bool z0 = is_init[(rb + l15) * T_ + s] != 0;
                const bool z1 = is_init[(rb + 16 + l15) * T_ + s] != 0;
                const __hip_bfloat16* r0 = hs + (size_t)(rb + l15) * H_ + kg;
                const __hip_bfloat16* r1 = hs + (size_t)(rb + 16 + l15) * H_ + kg;
                for (int k0 = 0; k0 < H_; k0 += 32) {
                    short8 a0 = *(const short8*)(r0 + k0);
                    short8 a1 = *(const short8*)(r1 + k0);
                    if (z0) a0 = zed;
                    if (z1) a1 = zed;
                    #pragma unroll
                    for (int g = 0; g < 3; ++g) {
                        short8 bf = *(const short8*)&wlds[(g * 16 + l15) * KPAD + 512 + k0 + kg];
                        acc[0][g] = __builtin_amdgcn_mfma_f32_16x16x32_bf16(a0, bf, acc[0][g], 0, 0, 0);
                        acc[1][g] = __builtin_amdgcn_mfma_f32_16x16x32_bf16(a1, bf, acc[1][g], 0, 0, 0);
                    }
                }
            }
        }

        __syncthreads();   // gi combine visible to h-waves

        if (active && part == 1) {
            __hip_bfloat16* Hout = (l ? h1b : h0b) + (size_t)(s & 1) * HS;
            #pragma unroll
            for (int mm = 0; mm < 2; ++mm) {
                #pragma unroll
                for (int r = 0; r < 4; ++r) {
                    const int row = mm * 16 + qr4 + r;
                    const int b = bt * 128 + mq * 32 + row;
                    const float* cp = &cmb[(mq * 32 + row) * CPAD];
                    const float gi_r = cp[l15];
                    const float gi_z = cp[16 + l15];
                    const float gi_n = cp[32 + l15];
                    const float rr = sigm(gi_r + acc[mm][0][r] + b_r);
                    const float zz = sigm(gi_z + acc[mm][1][r] + b_z);
                    const float nn = tanhf(gi_n + b_in + rr * (acc[mm][2][r] + b_hn));
                    const bool ini = is_init[b * T_ + s] != 0;
                    const float hprev = ini ? 0.0f : hp[mm][r];
                    const float hnew = (1.0f - zz) * nn + zz * hprev;
                    hp[mm][r] = hnew;
                    Hout[(size_t)b * H_ + j] = __float2bfloat16(hnew);
                    if (l) {
                        out[((size_t)b * T_ + s) * H_ + j] = hnew;
                        if (s == T_ - 1) out[OUT_MAIN + ((size_t)b * 2 + 1) * H_ + j] = hnew;
                    } else if (s == T_ - 1) {
                        out[OUT_MAIN + ((size_t)b * 2 + 0) * H_ + j] = hnew;
                    }
                }
            }
        }

        if (t < T_) group_barrier(&ctrs[bt * T_ + t], 64);
    }
}

extern "C" void kernel_launch(void* const* d_in, const int* in_sizes, int n_in,
                              void* d_out, int out_size, void* d_ws, size_t ws_size,
                              hipStream_t stream) {
    (void)in_sizes; (void)n_in; (void)out_size; (void)ws_size;
    const float* x    = (const float*)d_in[0];
    const int*   isin = (const int*)d_in[1];
    const float* h_in = (const float*)d_in[2];
    const float* wih0 = (const float*)d_in[3];
    const float* whh0 = (const float*)d_in[4];
    const float* bih0 = (const float*)d_in[5];
    const float* bhh0 = (const float*)d_in[6];
    const float* wih1 = (const float*)d_in[7];
    const float* whh1 = (const float*)d_in[8];
    const float* bih1 = (const float*)d_in[9];
    const float* bhh1 = (const float*)d_in[10];
    float* out = (float*)d_out;

    char* wsb = (char*)d_ws;
    __hip_bfloat16* h0b = (__hip_bfloat16*)wsb;            // 2 x [512*512] ping-pong
    __hip_bfloat16* h1b = h0b + 2 * HS;
    int* ctrs = (int*)(wsb + 4 * HS * 2);                  // 4 groups x 128 phases

    init_kernel<<<dim3(1024), dim3(256), 0, stream>>>(h_in, h0b, h1b, ctrs);

    gru_persist<<<dim3(256), dim3(512), 0, stream>>>(
        x, isin, h_in,
        wih0, whh0, bih0, bhh0,
        wih1, whh1, bih1, bhh1,
        h0b, h1b, ctrs, out);
}

// Round 3
// 2128.718 us; speedup vs baseline: 2.1275x; 1.4295x over previous
//
#include <hip/hip_runtime.h>
#include <hip/hip_bf16.h>

#define B_ 512
#define T_ 128
#define DIN_ 256
#define H_ 512
#define KPAD 1048          // LDS weight row stride (bf16): 524 dwords -> 2-way max conflict
#define WROWS 48           // 3 gates x 16 j
#define CPAD 52            // combine buffer row stride (f32)
#define HS ((size_t)B_ * H_)
#define OUT_MAIN ((size_t)B_ * T_ * H_)

typedef __attribute__((ext_vector_type(8))) short short8;
typedef __attribute__((ext_vector_type(4))) float f32x4;

__device__ __forceinline__ float sigm(float v) { return 1.0f / (1.0f + __expf(-v)); }

__device__ __forceinline__ unsigned short f2bf(float f) {
    union { __hip_bfloat16 b; unsigned short u; } c;
    c.b = __float2bfloat16(f);
    return c.u;
}

__device__ __forceinline__ short8 cvt8(const float* p) {
    f32x4 u = *(const f32x4*)p;
    f32x4 v = *(const f32x4*)(p + 4);
    short8 o;
    o[0] = (short)f2bf(u[0]); o[1] = (short)f2bf(u[1]);
    o[2] = (short)f2bf(u[2]); o[3] = (short)f2bf(u[3]);
    o[4] = (short)f2bf(v[0]); o[5] = (short)f2bf(v[1]);
    o[6] = (short)f2bf(v[2]); o[7] = (short)f2bf(v[3]);
    return o;
}

// 16B of h-state via two 8B agent-scope atomic loads (sc0 sc1: bypass L1+L2,
// served at the device-coherent point -> no cache fences needed anywhere).
__device__ __forceinline__ short8 load_h16(const __hip_bfloat16* p) {
    union { unsigned long long u[2]; short8 v; } r;
    r.u[0] = __hip_atomic_load((const unsigned long long*)p,       __ATOMIC_RELAXED, __HIP_MEMORY_SCOPE_AGENT);
    r.u[1] = __hip_atomic_load((const unsigned long long*)(p + 4), __ATOMIC_RELAXED, __HIP_MEMORY_SCOPE_AGENT);
    return r.v;
}

__device__ __forceinline__ void store_h8(__hip_bfloat16* p, const float* h4) {
    union { unsigned short s[4]; unsigned long long u; } r;
    r.s[0] = f2bf(h4[0]); r.s[1] = f2bf(h4[1]);
    r.s[2] = f2bf(h4[2]); r.s[3] = f2bf(h4[3]);
    __hip_atomic_store((unsigned long long*)p, r.u, __ATOMIC_RELAXED, __HIP_MEMORY_SCOPE_AGENT);
}

// Relaxed group barrier: NO release/acquire fences (no wbl2 / no L2 inv).
// Safe because all cross-block data moves via sc0sc1 (coherent-point) accesses
// and __syncthreads drains each wave's vmcnt before the counter increment.
__device__ __forceinline__ void group_barrier(int* c, int n) {
    __syncthreads();
    if (threadIdx.x == 0) {
        __hip_atomic_fetch_add(c, 1, __ATOMIC_RELAXED, __HIP_MEMORY_SCOPE_AGENT);
        while (__hip_atomic_load(c, __ATOMIC_RELAXED, __HIP_MEMORY_SCOPE_AGENT) < n)
            __builtin_amdgcn_s_sleep(1);
    }
    __syncthreads();
}

__global__ void init_kernel(const float* __restrict__ h_in,
                            __hip_bfloat16* __restrict__ h0b,
                            __hip_bfloat16* __restrict__ h1b,
                            int* __restrict__ ctrs)
{
    int i = blockIdx.x * blockDim.x + threadIdx.x;
    if (i < 512) ctrs[i] = 0;
    if (i < (int)(B_ * H_)) {
        int b = i >> 9, j = i & (H_ - 1);
        h0b[HS + i] = __float2bfloat16(h_in[((size_t)b * 2 + 0) * H_ + j]);
        h1b[HS + i] = __float2bfloat16(h_in[((size_t)b * 2 + 1) * H_ + j]);
    }
}

// Persistent kernel. 256 blocks x 512 threads, 1 block/CU (LDS-forced).
// block -> (layer l, batch-tile bt of 128 rows, j-tile jt of 16 cols)
// waves: mq in 0..3 (32 batch rows) x part (0 = input-side GEMM, 1 = hidden-side GEMM)
// MFMA operands SWAPPED: D[j][b] = mfma(W_frag, h_frag) -> lane holds 4 consecutive j.
__global__ __launch_bounds__(512) void gru_persist(
    const float* __restrict__ x, const int* __restrict__ is_init,
    const float* __restrict__ h_in,
    const float* __restrict__ wih0, const float* __restrict__ whh0,
    const float* __restrict__ bih0, const float* __restrict__ bhh0,
    const float* __restrict__ wih1, const float* __restrict__ whh1,
    const float* __restrict__ bih1, const float* __restrict__ bhh1,
    __hip_bfloat16* __restrict__ h0b, __hip_bfloat16* __restrict__ h1b,
    int* __restrict__ ctrs, float* __restrict__ out)
{
    __shared__ __hip_bfloat16 wlds[WROWS * KPAD];   // 100608 B
    __shared__ float cmb[128 * CPAD];               //  26624 B

    const int bid = blockIdx.x;
    const int l   = bid >> 7;
    const int bt  = (bid >> 5) & 3;
    const int jt  = bid & 31;
    const int tid = threadIdx.x;
    const int lane = tid & 63;
    const int wid  = tid >> 6;
    const int mq   = wid >> 1;
    const int part = wid & 1;
    const int l15  = lane & 15;
    const int kg   = (lane >> 4) * 8;   // k-chunk base within 32
    const int qr4  = (lane >> 4) * 4;   // j-quad base within 16
    const int rb   = bt * 128 + mq * 32;
    const int j4   = jt * 16 + qr4;     // first of this lane's 4 j columns

    const float* Wi = l ? wih1 : wih0;
    const float* Wh = l ? whh1 : whh0;
    const float* bi = l ? bih1 : bih0;
    const float* bh = l ? bhh1 : bhh0;
    const int KI = l ? H_ : DIN_;

    // ---- stage weight slice to LDS (f32 -> bf16), once ----
    {
        const int nci = KI / 8;
        for (int idx = tid; idx < WROWS * nci; idx += 512) {
            int r = idx / nci, c8 = idx - r * nci;
            int grow = (r >> 4) * H_ + jt * 16 + (r & 15);
            *(short8*)&wlds[r * KPAD + c8 * 8] = cvt8(Wi + (size_t)grow * KI + c8 * 8);
        }
        for (int idx = tid; idx < WROWS * 64; idx += 512) {
            int r = idx >> 6, c8 = idx & 63;
            int grow = (r >> 4) * H_ + jt * 16 + (r & 15);
            *(short8*)&wlds[r * KPAD + KI + c8 * 8] = cvt8(Wh + (size_t)grow * H_ + c8 * 8);
        }
    }

    // ---- hoisted per-lane constants (j4..j4+3 columns) ----
    const f32x4 b_r  = *(const f32x4*)&bi[j4]          + *(const f32x4*)&bh[j4];
    const f32x4 b_z  = *(const f32x4*)&bi[H_ + j4]     + *(const f32x4*)&bh[H_ + j4];
    const f32x4 b_in = *(const f32x4*)&bi[2 * H_ + j4];
    const f32x4 b_hn = *(const f32x4*)&bh[2 * H_ + j4];

    // f32 master state: rows b = rb + mm*16 + l15, cols j4..j4+3
    f32x4 hp[2];
    #pragma unroll
    for (int mm = 0; mm < 2; ++mm)
        hp[mm] = *(const f32x4*)&h_in[((size_t)(rb + mm * 16 + l15) * 2 + l) * H_ + j4];

    __syncthreads();

    const short8 zed = {0, 0, 0, 0, 0, 0, 0, 0};

    for (int t = 0; t <= T_; ++t) {
        const int s = l ? (t - 1) : t;
        const bool active = (s >= 0) && (s < T_);

        f32x4 acc[2][3];
        #pragma unroll
        for (int mm = 0; mm < 2; ++mm)
            #pragma unroll
            for (int g = 0; g < 3; ++g)
                acc[mm][g] = f32x4{0.f, 0.f, 0.f, 0.f};

        if (active) {
            if (part == 0) {
                // ---- input-side GEMM (gi) ----
                if (l == 0) {
                    const float* xr0 = x + ((size_t)(rb + l15) * T_ + s) * DIN_ + kg;
                    const float* xr1 = x + ((size_t)(rb + 16 + l15) * T_ + s) * DIN_ + kg;
                    #pragma unroll
                    for (int k0 = 0; k0 < DIN_; k0 += 32) {
                        short8 a0 = cvt8(xr0 + k0);
                        short8 a1 = cvt8(xr1 + k0);
                        #pragma unroll
                        for (int g = 0; g < 3; ++g) {
                            short8 wf = *(const short8*)&wlds[(g * 16 + l15) * KPAD + k0 + kg];
                            acc[0][g] = __builtin_amdgcn_mfma_f32_16x16x32_bf16(wf, a0, acc[0][g], 0, 0, 0);
                            acc[1][g] = __builtin_amdgcn_mfma_f32_16x16x32_bf16(wf, a1, acc[1][g], 0, 0, 0);
                        }
                    }
                } else {
                    const __hip_bfloat16* hs = h0b + (size_t)(s & 1) * HS;
                    const __hip_bfloat16* r0 = hs + (size_t)(rb + l15) * H_ + kg;
                    const __hip_bfloat16* r1 = hs + (size_t)(rb + 16 + l15) * H_ + kg;
                    #pragma unroll
                    for (int k0 = 0; k0 < H_; k0 += 32) {
                        short8 a0 = load_h16(r0 + k0);
                        short8 a1 = load_h16(r1 + k0);
                        #pragma unroll
                        for (int g = 0; g < 3; ++g) {
                            short8 wf = *(const short8*)&wlds[(g * 16 + l15) * KPAD + k0 + kg];
                            acc[0][g] = __builtin_amdgcn_mfma_f32_16x16x32_bf16(wf, a0, acc[0][g], 0, 0, 0);
                            acc[1][g] = __builtin_amdgcn_mfma_f32_16x16x32_bf16(wf, a1, acc[1][g], 0, 0, 0);
                        }
                    }
                }
                // dump gi to combine buffer: row = b-local, col = g*16 + j-quad
                #pragma unroll
                for (int mm = 0; mm < 2; ++mm)
                    #pragma unroll
                    for (int g = 0; g < 3; ++g)
                        *(f32x4*)&cmb[(mq * 32 + mm * 16 + l15) * CPAD + g * 16 + qr4] = acc[mm][g];
            } else {
                // ---- hidden-side GEMM (gh), per-row is_init zeroing ----
                const __hip_bfloat16* hs = (l ? h1b : h0b) + (size_t)((s + 1) & 1) * HS;
                const bool z0 = is_init[(rb + l15) * T_ + s] != 0;
                const bool z1 = is_init[(rb + 16 + l15) * T_ + s] != 0;
                const __hip_bfloat16* r0 = hs + (size_t)(rb + l15) * H_ + kg;
                const __hip_bfloat16* r1 = hs + (size_t)(rb + 16 + l15) * H_ + kg;
                #pragma unroll
                for (int k0 = 0; k0 < H_; k0 += 32) {
                    short8 a0 = z0 ? zed : load_h16(r0 + k0);
                    short8 a1 = z1 ? zed : load_h16(r1 + k0);
                    #pragma unroll
                    for (int g = 0; g < 3; ++g) {
                        short8 wf = *(const short8*)&wlds[(g * 16 + l15) * KPAD + KI + k0 + kg];
                        acc[0][g] = __builtin_amdgcn_mfma_f32_16x16x32_bf16(wf, a0, acc[0][g], 0, 0, 0);
                        acc[1][g] = __builtin_amdgcn_mfma_f32_16x16x32_bf16(wf, a1, acc[1][g], 0, 0, 0);
                    }
                }
            }
        }

        __syncthreads();   // gi combine visible to gh waves

        if (active && part == 1) {
            __hip_bfloat16* Hout = (l ? h1b : h0b) + (size_t)(s & 1) * HS;
            #pragma unroll
            for (int mm = 0; mm < 2; ++mm) {
                const int b = rb + mm * 16 + l15;
                const bool ini = is_init[b * T_ + s] != 0;
                const float* cp = &cmb[(mq * 32 + mm * 16 + l15) * CPAD + qr4];
                const f32x4 gi_r = *(const f32x4*)(cp);
                const f32x4 gi_z = *(const f32x4*)(cp + 16);
                const f32x4 gi_n = *(const f32x4*)(cp + 32);
                float hv[4];
                #pragma unroll
                for (int r = 0; r < 4; ++r) {
                    const float rr = sigm(gi_r[r] + acc[mm][0][r] + b_r[r]);
                    const float zz = sigm(gi_z[r] + acc[mm][1][r] + b_z[r]);
                    const float nn = tanhf(gi_n[r] + b_in[r] + rr * (acc[mm][2][r] + b_hn[r]));
                    const float hprev = ini ? 0.0f : hp[mm][r];
                    hv[r] = (1.0f - zz) * nn + zz * hprev;
                    hp[mm][r] = hv[r];
                }
                store_h8(&Hout[(size_t)b * H_ + j4], hv);
                if (l) {
                    *(f32x4*)&out[((size_t)b * T_ + s) * H_ + j4] = f32x4{hv[0], hv[1], hv[2], hv[3]};
                    if (s == T_ - 1)
                        *(f32x4*)&out[OUT_MAIN + ((size_t)b * 2 + 1) * H_ + j4] = f32x4{hv[0], hv[1], hv[2], hv[3]};
                } else if (s == T_ - 1) {
                    *(f32x4*)&out[OUT_MAIN + ((size_t)b * 2 + 0) * H_ + j4] = f32x4{hv[0], hv[1], hv[2], hv[3]};
                }
            }
        }

        if (t < T_) group_barrier(&ctrs[bt * T_ + t], 64);
    }
}

extern "C" void kernel_launch(void* const* d_in, const int* in_sizes, int n_in,
                              void* d_out, int out_size, void* d_ws, size_t ws_size,
                              hipStream_t stream) {
    (void)in_sizes; (void)n_in; (void)out_size; (void)ws_size;
    const float* x    = (const float*)d_in[0];
    const int*   isin = (const int*)d_in[1];
    const float* h_in = (const float*)d_in[2];
    const float* wih0 = (const float*)d_in[3];
    const float* whh0 = (const float*)d_in[4];
    const float* bih0 = (const float*)d_in[5];
    const float* bhh0 = (const float*)d_in[6];
    const float* wih1 = (const float*)d_in[7];
    const float* whh1 = (const float*)d_in[8];
    const float* bih1 = (const float*)d_in[9];
    const float* bhh1 = (const float*)d_in[10];
    float* out = (float*)d_out;

    char* wsb = (char*)d_ws;
    __hip_bfloat16* h0b = (__hip_bfloat16*)wsb;            // 2 x [512*512] ping-pong
    __hip_bfloat16* h1b = h0b + 2 * HS;
    int* ctrs = (int*)(wsb + 4 * HS * 2);                  // 4 groups x 128 phases

    init_kernel<<<dim3(1024), dim3(256), 0, stream>>>(h_in, h0b, h1b, ctrs);

    gru_persist<<<dim3(256), dim3(512), 0, stream>>>(
        x, isin, h_in,
        wih0, whh0, bih0, bhh0,
        wih1, whh1, bih1, bhh1,
        h0b, h1b, ctrs, out);
}